// Round 5
// baseline (250.308 us; speedup 1.0000x reference)
//
#include <hip/hip_runtime.h>

// region_pooling via scatter + dense GEMM + split-k partials.
// F: [B=8, HW=4096, C=1024] fp32 (H=W=64); pc: [B, M=32, P=512, 2]
// out[b,m,c] = sum_hw W[b][hw][m] * F[b][hw][c]; W = scattered bilinear
// weights pre-scaled by 1/P.
//
// v5: same decomposition as v4 (wave = m-octet, 8 channels/lane; per
// hw-step per thread: 2 wave-uniform ds_read_b128 of W + 2 global dwordx4
// of F + 64 FMA) but WITHOUT the hand-rolled W register double-buffer —
// compiler schedules the unrolled ds_reads itself.

#define NB 8
#define NM 32
#define NP 512
#define NC 1024
#define NH 64
#define NHW 4096

#define KC    128                 // hw per k-chunk
#define NKC   (NHW / KC)          // 32 k-chunks
#define CPT   8                   // channels per lane
#define MT    8                   // m's per wave (NM/4 waves)
#define CTILE 512                 // c-extent per block (64 lanes * CPT)
#define NCT   (NC / CTILE)        // 2 c-tiles
#define PF    4                   // F prefetch depth (steps)

// ---- Phase 1: scatter bilinear weights into W[b][hw][m] (pre-zeroed) ----
__global__ __launch_bounds__(256) void scatter_w(
    const float* __restrict__ pc, float* __restrict__ W)
{
    int idx = blockIdx.x * 256 + threadIdx.x;   // [0, B*M*P)
    int bm  = idx >> 9;                         // b*NM + m
    int m   = bm & (NM - 1);
    int b   = bm >> 5;

    float2 c = ((const float2*)pc)[idx];
    float y = c.x * 63.0f;
    float x = c.y * 63.0f;
    float x0f = floorf(x), y0f = floorf(y);
    float wx = x - x0f, wy = y - y0f;
    int ix0 = min(max((int)x0f, 0), 63);
    int ix1 = min(ix0 + 1, 63);
    int iy0 = min(max((int)y0f, 0), 63);
    int iy1 = min(iy0 + 1, 63);
    float wx1 = 1.0f - wx, wy1 = 1.0f - wy;
    const float s = 1.0f / (float)NP;           // fold the mean here

    float* Wb = W + (size_t)b * (NHW * NM) + m;
    atomicAdd(Wb + ((iy0 * NH + ix0) * NM), wx1 * wy1 * s);
    atomicAdd(Wb + ((iy0 * NH + ix1) * NM), wx  * wy1 * s);
    atomicAdd(Wb + ((iy1 * NH + ix0) * NM), wx1 * wy  * s);
    atomicAdd(Wb + ((iy1 * NH + ix1) * NM), wx  * wy  * s);
}

// ---- Phase 2: P[kc][b][m][c] = sum_{hw in chunk kc} W[b][hw][m]*F[b][hw][c]
// Grid (NKC, NCT, NB) = (32, 2, 8) = 512 blocks, 256 thr = 4 waves; 2 blk/CU.
// Wave w owns m in [w*8, w*8+8); lane owns 8 channels. W chunk (16 KB) in
// LDS; per-step W read is one wave-uniform 32 B broadcast (2 b128).
__global__ __launch_bounds__(256, 2) void wgemm(
    const float* __restrict__ W, const float* __restrict__ F,
    float* __restrict__ P)
{
    __shared__ float sW[KC * NM];               // 16 KB

    const int kc   = blockIdx.x;                // 32 k-chunks
    const int ct   = blockIdx.y;                // 2 c-tiles
    const int b    = blockIdx.z;
    const int tid  = threadIdx.x;
    const int mq   = tid >> 6;                  // wave id = m-octet
    const int lane = tid & 63;
    const int c0   = ct * CTILE + lane * CPT;
    const int hw0  = kc * KC;

    // stage W[hw0:hw0+KC][0:32] -> LDS (4096 floats = 1024 float4)
    {
        const float4* Wg = (const float4*)(W + ((size_t)b * NHW + hw0) * NM);
        float4* sW4 = (float4*)sW;
#pragma unroll
        for (int j = 0; j < 4; ++j)
            sW4[tid + 256 * j] = Wg[tid + 256 * j];
    }
    __syncthreads();

    const float4* __restrict__ Fb =
        (const float4*)(F + ((size_t)b * NHW + hw0) * NC + c0);
    const int fstride = NC / 4;                 // float4 stride per hw row

    float4 acc[MT][2];
#pragma unroll
    for (int m = 0; m < MT; ++m) {
        acc[m][0] = make_float4(0.f, 0.f, 0.f, 0.f);
        acc[m][1] = make_float4(0.f, 0.f, 0.f, 0.f);
    }

    // F prefetch ring, PF steps deep
    float4 fbuf[PF][2];
#pragma unroll
    for (int j = 0; j < PF; ++j) {
        fbuf[j][0] = Fb[(size_t)j * fstride];
        fbuf[j][1] = Fb[(size_t)j * fstride + 1];
    }

    // W row base for this wave: row stride NM floats, wave offset mq*MT
    const float4* sWq = (const float4*)(sW + mq * MT);

    for (int i = 0; i < KC; i += PF) {
#pragma unroll
        for (int j = 0; j < PF; ++j) {
            const int s = i + j;
            // wave-uniform broadcast read of this step's 8 weights
            float4 wa0 = sWq[(size_t)s * (NM / 4)];
            float4 wa1 = sWq[(size_t)s * (NM / 4) + 1];

            float4 f0 = fbuf[j][0];
            float4 f1 = fbuf[j][1];
            if (i + PF < KC) {
                fbuf[j][0] = Fb[(size_t)(s + PF) * fstride];
                fbuf[j][1] = Fb[(size_t)(s + PF) * fstride + 1];
            }

            const float wm[MT] = { wa0.x, wa0.y, wa0.z, wa0.w,
                                   wa1.x, wa1.y, wa1.z, wa1.w };
#pragma unroll
            for (int m = 0; m < MT; ++m) {
                float w = wm[m];
                acc[m][0].x = fmaf(w, f0.x, acc[m][0].x);
                acc[m][0].y = fmaf(w, f0.y, acc[m][0].y);
                acc[m][0].z = fmaf(w, f0.z, acc[m][0].z);
                acc[m][0].w = fmaf(w, f0.w, acc[m][0].w);
                acc[m][1].x = fmaf(w, f1.x, acc[m][1].x);
                acc[m][1].y = fmaf(w, f1.y, acc[m][1].y);
                acc[m][1].z = fmaf(w, f1.z, acc[m][1].z);
                acc[m][1].w = fmaf(w, f1.w, acc[m][1].w);
            }
        }
    }

    // partials: P[((kc*NB + b)*NM + m)*NC + c], m = mq*8 + mm
    float* pb = P + (((size_t)kc * NB + b) * NM + mq * MT) * NC + c0;
#pragma unroll
    for (int mm = 0; mm < MT; ++mm) {
        ((float4*)(pb + (size_t)mm * NC))[0] = acc[mm][0];
        ((float4*)(pb + (size_t)mm * NC))[1] = acc[mm][1];
    }
}

// ---- Phase 3: out = sum over the 32 k-chunk partials ----
__global__ __launch_bounds__(256) void reduce_p(
    const float* __restrict__ P, float* __restrict__ out)
{
    const int idx = blockIdx.x * 256 + threadIdx.x;   // [0, NB*NM*NC/4)
    const float4* p4 = (const float4*)P;
    const int stride = NB * NM * NC / 4;              // 65536
    float4 s = make_float4(0.f, 0.f, 0.f, 0.f);
#pragma unroll
    for (int kc = 0; kc < NKC; ++kc) {
        float4 v = p4[(size_t)kc * stride + idx];
        s.x += v.x; s.y += v.y; s.z += v.z; s.w += v.w;
    }
    ((float4*)out)[idx] = s;
}

// ---- Fallback (ws too small): direct gather ----
__global__ __launch_bounds__(256) void region_pool_direct(
    const float* __restrict__ fm, const float* __restrict__ pc,
    float* __restrict__ out)
{
    __shared__ int4   sIdx[NP];
    __shared__ float4 sWt[NP];
    const int bid = blockIdx.x;
    const int b   = bid >> 5;
    const int tid = threadIdx.x;
    const float2* pc2 = (const float2*)(pc + (size_t)bid * NP * 2);
    for (int p = tid; p < NP; p += 256) {
        float2 c = pc2[p];
        float y = c.x * 63.0f, x = c.y * 63.0f;
        float x0f = floorf(x), y0f = floorf(y);
        float wx = x - x0f, wy = y - y0f;
        int ix0 = min(max((int)x0f, 0), 63);
        int ix1 = min(ix0 + 1, 63);
        int iy0 = min(max((int)y0f, 0), 63);
        int iy1 = min(iy0 + 1, 63);
        sIdx[p] = make_int4((iy0 * NH + ix0) << 10, (iy0 * NH + ix1) << 10,
                            (iy1 * NH + ix0) << 10, (iy1 * NH + ix1) << 10);
        float wx1 = 1.0f - wx, wy1 = 1.0f - wy;
        sWt[p] = make_float4(wx1 * wy1, wx * wy1, wx1 * wy, wx * wy);
    }
    __syncthreads();
    const float* Fb = fm + (size_t)b * (NHW * NC) + tid * 4;
    float4 acc = make_float4(0.f, 0.f, 0.f, 0.f);
#pragma unroll 4
    for (int p = 0; p < NP; ++p) {
        int4 off = sIdx[p]; float4 w = sWt[p];
        float4 f00 = *(const float4*)(Fb + off.x);
        float4 f01 = *(const float4*)(Fb + off.y);
        float4 f10 = *(const float4*)(Fb + off.z);
        float4 f11 = *(const float4*)(Fb + off.w);
        acc.x = fmaf(w.x, f00.x, fmaf(w.y, f01.x, fmaf(w.z, f10.x, fmaf(w.w, f11.x, acc.x))));
        acc.y = fmaf(w.x, f00.y, fmaf(w.y, f01.y, fmaf(w.z, f10.y, fmaf(w.w, f11.y, acc.y))));
        acc.z = fmaf(w.x, f00.z, fmaf(w.y, f01.z, fmaf(w.z, f10.z, fmaf(w.w, f11.z, acc.z))));
        acc.w = fmaf(w.x, f00.w, fmaf(w.y, f01.w, fmaf(w.z, f10.w, fmaf(w.w, f11.w, acc.w))));
    }
    const float inv = 1.0f / (float)NP;
    ((float4*)(out + (size_t)bid * NC))[tid] =
        make_float4(acc.x * inv, acc.y * inv, acc.z * inv, acc.w * inv);
}

extern "C" void kernel_launch(void* const* d_in, const int* in_sizes, int n_in,
                              void* d_out, int out_size, void* d_ws, size_t ws_size,
                              hipStream_t stream) {
    const float* fm = (const float*)d_in[0];   // [8, 4096, 1024]
    const float* pc = (const float*)d_in[1];   // [8, 32, 512, 2]
    float* out = (float*)d_out;                // [8, 32, 1, 1024]

    const size_t wbytes = (size_t)NB * NHW * NM * sizeof(float);           // 4 MB
    const size_t pbytes = (size_t)NKC * NB * NM * NC * sizeof(float);      // 32 MB
    if (ws_size >= wbytes + pbytes) {
        float* W = (float*)d_ws;
        float* P = (float*)((char*)d_ws + wbytes);
        hipMemsetAsync(W, 0, wbytes, stream);
        scatter_w<<<(NB * NM * NP) / 256, 256, 0, stream>>>(pc, W);
        dim3 grid(NKC, NCT, NB);
        wgemm<<<grid, 256, 0, stream>>>(W, fm, P);
        reduce_p<<<(NB * NM * NC / 4) / 256, 256, 0, stream>>>(P, out);
    } else {
        region_pool_direct<<<NB * NM, 256, 0, stream>>>(fm, pc, out);
    }
}

// Round 6
// 233.430 us; speedup vs baseline: 1.0723x; 1.0723x over previous
//
#include <hip/hip_runtime.h>

// region_pooling via scatter + dense GEMM + split-k partials.
// F: [B=8, HW=4096, C=1024] fp32 (H=W=64); pc: [B, M=32, P=512, 2]
// out[b,m,c] = sum_hw W[b][hw][m] * F[b][hw][c]; W = scattered bilinear
// weights pre-scaled by 1/P.
//
// v6: F staged into LDS via global_load_lds (async DMA, zero VGPR cost),
// double-buffered in 8-row chunks; W broadcast from LDS as before.
// Lane owns channels {4*lane..4*lane+3} and {256+4*lane..}: sF reads are
// stride-16B conflict-free, P writes perfectly coalesced.

#define NB 8
#define NM 32
#define NP 512
#define NC 1024
#define NH 64
#define NHW 4096

#define KC     128                // hw per k-chunk
#define NKC    (NHW / KC)         // 32 k-chunks
#define MT     8                  // m's per wave (4 waves)
#define CTILE  512                // channels per block
#define NCT    (NC / CTILE)       // 2 c-tiles
#define G      8                  // rows per DMA chunk
#define NCHUNK (KC / G)           // 16 chunks

// ---- Phase 1: scatter bilinear weights into W[b][hw][m] (pre-zeroed) ----
__global__ __launch_bounds__(256) void scatter_w(
    const float* __restrict__ pc, float* __restrict__ W)
{
    int idx = blockIdx.x * 256 + threadIdx.x;   // [0, B*M*P)
    int bm  = idx >> 9;                         // b*NM + m
    int m   = bm & (NM - 1);
    int b   = bm >> 5;

    float2 c = ((const float2*)pc)[idx];
    float y = c.x * 63.0f;
    float x = c.y * 63.0f;
    float x0f = floorf(x), y0f = floorf(y);
    float wx = x - x0f, wy = y - y0f;
    int ix0 = min(max((int)x0f, 0), 63);
    int ix1 = min(ix0 + 1, 63);
    int iy0 = min(max((int)y0f, 0), 63);
    int iy1 = min(iy0 + 1, 63);
    float wx1 = 1.0f - wx, wy1 = 1.0f - wy;
    const float s = 1.0f / (float)NP;           // fold the mean here

    float* Wb = W + (size_t)b * (NHW * NM) + m;
    atomicAdd(Wb + ((iy0 * NH + ix0) * NM), wx1 * wy1 * s);
    atomicAdd(Wb + ((iy0 * NH + ix1) * NM), wx  * wy1 * s);
    atomicAdd(Wb + ((iy1 * NH + ix0) * NM), wx1 * wy  * s);
    atomicAdd(Wb + ((iy1 * NH + ix1) * NM), wx  * wy  * s);
}

// stage 2 rows x 512 floats of F into LDS via async DMA (one wave's share)
__device__ __forceinline__ void dma_rows(const float* src, float* dstBase,
                                         int lane)
{
#pragma unroll
    for (int jj = 0; jj < 2; ++jj) {
        const float* s0 = src + jj * NC + lane * 4;
        const float* s1 = src + jj * NC + 256 + lane * 4;
        float* d0 = dstBase + jj * CTILE + lane * 4;
        float* d1 = dstBase + jj * CTILE + 256 + lane * 4;
        __builtin_amdgcn_global_load_lds(
            (const __attribute__((address_space(1))) void*)s0,
            (__attribute__((address_space(3))) void*)d0, 16, 0, 0);
        __builtin_amdgcn_global_load_lds(
            (const __attribute__((address_space(1))) void*)s1,
            (__attribute__((address_space(3))) void*)d1, 16, 0, 0);
    }
}

// ---- Phase 2: P[kc][b][m][c] = sum_{hw in chunk kc} W[b][hw][m]*F[b][hw][c]
// Grid (NKC, NCT, NB) = (32, 2, 8) = 512 blocks, 256 thr = 4 waves, 2 blk/CU.
// Wave mq owns m in [mq*8, mq*8+8); lane owns channels 4*lane and 256+4*lane
// (two float4). F double-buffered in LDS via global_load_lds, 8-row chunks.
__global__ __launch_bounds__(256, 2) void wgemm(
    const float* __restrict__ W, const float* __restrict__ F,
    float* __restrict__ P)
{
    __shared__ float sW[KC * NM];               // 16 KB
    __shared__ float sF[2][G][CTILE];           // 32 KB

    const int kc   = blockIdx.x;
    const int ct   = blockIdx.y;
    const int b    = blockIdx.z;
    const int tid  = threadIdx.x;
    const int mq   = tid >> 6;                  // wave id = m-octet
    const int lane = tid & 63;
    const int hw0  = kc * KC;

    // stage W[hw0:hw0+KC][0:32] -> LDS (1024 float4, 4 per thread)
    {
        const float4* Wg = (const float4*)(W + ((size_t)b * NHW + hw0) * NM);
        float4* sW4 = (float4*)sW;
#pragma unroll
        for (int j = 0; j < 4; ++j)
            sW4[tid + 256 * j] = Wg[tid + 256 * j];
    }

    const float* Fbase = F + ((size_t)b * NHW + hw0) * NC + ct * CTILE;

    // DMA chunk 0 (wave mq stages rows mq*2, mq*2+1)
    dma_rows(Fbase + (size_t)(mq * 2) * NC, &sF[0][mq * 2][0], lane);
    __syncthreads();                            // drains lgkm (W) + vm (DMA)

    float4 acc[MT][2];
#pragma unroll
    for (int m = 0; m < MT; ++m) {
        acc[m][0] = make_float4(0.f, 0.f, 0.f, 0.f);
        acc[m][1] = make_float4(0.f, 0.f, 0.f, 0.f);
    }

    int buf = 0;
    for (int t = 0; t < NCHUNK; ++t) {
        // issue next chunk's DMA (writes buf^1, which everyone finished
        // reading before the barrier that ended iteration t-1)
        if (t + 1 < NCHUNK)
            dma_rows(Fbase + (size_t)((t + 1) * G + mq * 2) * NC,
                     &sF[buf ^ 1][mq * 2][0], lane);

        const float* sWrow = sW + (t * G) * NM + mq * MT;
#pragma unroll
        for (int j = 0; j < G; ++j) {
            float4 w0 = *(const float4*)(sWrow + j * NM);
            float4 w1 = *(const float4*)(sWrow + j * NM + 4);
            float4 f0 = *(const float4*)(&sF[buf][j][4 * lane]);
            float4 f1 = *(const float4*)(&sF[buf][j][256 + 4 * lane]);
            const float wm[MT] = { w0.x, w0.y, w0.z, w0.w,
                                   w1.x, w1.y, w1.z, w1.w };
#pragma unroll
            for (int m = 0; m < MT; ++m) {
                float w = wm[m];
                acc[m][0].x = fmaf(w, f0.x, acc[m][0].x);
                acc[m][0].y = fmaf(w, f0.y, acc[m][0].y);
                acc[m][0].z = fmaf(w, f0.z, acc[m][0].z);
                acc[m][0].w = fmaf(w, f0.w, acc[m][0].w);
                acc[m][1].x = fmaf(w, f1.x, acc[m][1].x);
                acc[m][1].y = fmaf(w, f1.y, acc[m][1].y);
                acc[m][1].z = fmaf(w, f1.z, acc[m][1].z);
                acc[m][1].w = fmaf(w, f1.w, acc[m][1].w);
            }
        }
        __syncthreads();                        // drain DMA + all LDS reads
        buf ^= 1;
    }

    // partials: P[((kc*NB + b)*NM + m)*NC + c]; coalesced float4 stores
    float* pb = P + (((size_t)kc * NB + b) * NM + mq * MT) * NC + ct * CTILE;
#pragma unroll
    for (int mm = 0; mm < MT; ++mm) {
        *(float4*)(pb + (size_t)mm * NC + 4 * lane)       = acc[mm][0];
        *(float4*)(pb + (size_t)mm * NC + 256 + 4 * lane) = acc[mm][1];
    }
}

// ---- Phase 3: out = sum over the 32 k-chunk partials ----
__global__ __launch_bounds__(256) void reduce_p(
    const float* __restrict__ P, float* __restrict__ out)
{
    const int idx = blockIdx.x * 256 + threadIdx.x;   // [0, NB*NM*NC/4)
    const float4* p4 = (const float4*)P;
    const int stride = NB * NM * NC / 4;              // 65536
    float4 s = make_float4(0.f, 0.f, 0.f, 0.f);
#pragma unroll
    for (int kc = 0; kc < NKC; ++kc) {
        float4 v = p4[(size_t)kc * stride + idx];
        s.x += v.x; s.y += v.y; s.z += v.z; s.w += v.w;
    }
    ((float4*)out)[idx] = s;
}

// ---- Fallback (ws too small): direct gather ----
__global__ __launch_bounds__(256) void region_pool_direct(
    const float* __restrict__ fm, const float* __restrict__ pc,
    float* __restrict__ out)
{
    __shared__ int4   sIdx[NP];
    __shared__ float4 sWt[NP];
    const int bid = blockIdx.x;
    const int b   = bid >> 5;
    const int tid = threadIdx.x;
    const float2* pc2 = (const float2*)(pc + (size_t)bid * NP * 2);
    for (int p = tid; p < NP; p += 256) {
        float2 c = pc2[p];
        float y = c.x * 63.0f, x = c.y * 63.0f;
        float x0f = floorf(x), y0f = floorf(y);
        float wx = x - x0f, wy = y - y0f;
        int ix0 = min(max((int)x0f, 0), 63);
        int ix1 = min(ix0 + 1, 63);
        int iy0 = min(max((int)y0f, 0), 63);
        int iy1 = min(iy0 + 1, 63);
        sIdx[p] = make_int4((iy0 * NH + ix0) << 10, (iy0 * NH + ix1) << 10,
                            (iy1 * NH + ix0) << 10, (iy1 * NH + ix1) << 10);
        float wx1 = 1.0f - wx, wy1 = 1.0f - wy;
        sWt[p] = make_float4(wx1 * wy1, wx * wy1, wx1 * wy, wx * wy);
    }
    __syncthreads();
    const float* Fb = fm + (size_t)b * (NHW * NC) + tid * 4;
    float4 acc = make_float4(0.f, 0.f, 0.f, 0.f);
#pragma unroll 4
    for (int p = 0; p < NP; ++p) {
        int4 off = sIdx[p]; float4 w = sWt[p];
        float4 f00 = *(const float4*)(Fb + off.x);
        float4 f01 = *(const float4*)(Fb + off.y);
        float4 f10 = *(const float4*)(Fb + off.z);
        float4 f11 = *(const float4*)(Fb + off.w);
        acc.x = fmaf(w.x, f00.x, fmaf(w.y, f01.x, fmaf(w.z, f10.x, fmaf(w.w, f11.x, acc.x))));
        acc.y = fmaf(w.x, f00.y, fmaf(w.y, f01.y, fmaf(w.z, f10.y, fmaf(w.w, f11.y, acc.y))));
        acc.z = fmaf(w.x, f00.z, fmaf(w.y, f01.z, fmaf(w.z, f10.z, fmaf(w.w, f11.z, acc.z))));
        acc.w = fmaf(w.x, f00.w, fmaf(w.y, f01.w, fmaf(w.z, f10.w, fmaf(w.w, f11.w, acc.w))));
    }
    const float inv = 1.0f / (float)NP;
    ((float4*)(out + (size_t)bid * NC))[tid] =
        make_float4(acc.x * inv, acc.y * inv, acc.z * inv, acc.w * inv);
}

extern "C" void kernel_launch(void* const* d_in, const int* in_sizes, int n_in,
                              void* d_out, int out_size, void* d_ws, size_t ws_size,
                              hipStream_t stream) {
    const float* fm = (const float*)d_in[0];   // [8, 4096, 1024]
    const float* pc = (const float*)d_in[1];   // [8, 32, 512, 2]
    float* out = (float*)d_out;                // [8, 32, 1, 1024]

    const size_t wbytes = (size_t)NB * NHW * NM * sizeof(float);           // 4 MB
    const size_t pbytes = (size_t)NKC * NB * NM * NC * sizeof(float);      // 32 MB
    if (ws_size >= wbytes + pbytes) {
        float* W = (float*)d_ws;
        float* P = (float*)((char*)d_ws + wbytes);
        hipMemsetAsync(W, 0, wbytes, stream);
        scatter_w<<<(NB * NM * NP) / 256, 256, 0, stream>>>(pc, W);
        dim3 grid(NKC, NCT, NB);
        wgemm<<<grid, 256, 0, stream>>>(W, fm, P);
        reduce_p<<<(NB * NM * NC / 4) / 256, 256, 0, stream>>>(P, out);
    } else {
        region_pool_direct<<<NB * NM, 256, 0, stream>>>(fm, pc, out);
    }
}